// Round 1
// 568.712 us; speedup vs baseline: 1.0789x; 1.0789x over previous
//
#include <hip/hip_runtime.h>
#include <hip/hip_bf16.h>
#include <stdint.h>

#define B_SZ 32
#define S_SZ 2048
#define H_SZ 1024
#define K_SZ 1024
#define M_SZ (B_SZ * S_SZ)   // 65536 rows of the big GEMM

typedef __attribute__((ext_vector_type(8))) short bf16x8;   // 8 bf16 = 4 VGPRs (MFMA A/B frag)
typedef __attribute__((ext_vector_type(4))) float f32x4;    // MFMA C/D frag

// ---- helpers ----------------------------------------------------------------

__device__ __forceinline__ short f2bf_rne(float f) {
    uint32_t u = __builtin_bit_cast(uint32_t, f);
    u += 0x7fffu + ((u >> 16) & 1u);   // round-to-nearest-even
    return (short)(u >> 16);
}

__device__ __forceinline__ float bf2f(unsigned short u) {
    return __builtin_bit_cast(float, (uint32_t)u << 16);
}

__device__ __forceinline__ float fast_tanh(float x) {
    // tanh(x) = 1 - 2/(exp(2x)+1); exact limits at +-inf, ~1e-6 rel err.
    float ex = __expf(2.0f * x);
    return 1.0f - 2.0f / (ex + 1.0f);
}

// ---- fp32 -> bf16 conversion (8 elems/thread, grid-stride) ------------------

__global__ void cvt_bf16_k(const float* __restrict__ in,
                           __hip_bfloat16* __restrict__ out, int n8) {
    int idx = blockIdx.x * blockDim.x + threadIdx.x;
    int stride = gridDim.x * blockDim.x;
    for (int i = idx; i < n8; i += stride) {
        const float4* p = (const float4*)in + (size_t)i * 2;
        float4 a = p[0], b = p[1];
        bf16x8 r;
        r[0] = f2bf_rne(a.x); r[1] = f2bf_rne(a.y);
        r[2] = f2bf_rne(a.z); r[3] = f2bf_rne(a.w);
        r[4] = f2bf_rne(b.x); r[5] = f2bf_rne(b.y);
        r[6] = f2bf_rne(b.z); r[7] = f2bf_rne(b.w);
        ((bf16x8*)out)[i] = r;
    }
}

// ---- dec_proj[b][k] = dot(dec[b,:], Wb[k,:]) + Wb_b[k] + Wc_b[k] ------------
// one wave per output; coalesced float4 + shfl reduce

__global__ __launch_bounds__(256) void decproj_k(
    const float* __restrict__ ds, const float* __restrict__ Wb,
    const float* __restrict__ Wb_b, const float* __restrict__ Wc_b,
    float* __restrict__ dp) {
    int g = blockIdx.x * 4 + (threadIdx.x >> 6);   // wave id = output id
    int lane = threadIdx.x & 63;
    int b = g >> 10;
    int k = g & 1023;
    const float4* wrow = (const float4*)(Wb + (size_t)k * H_SZ);
    const float4* xrow = (const float4*)(ds + (size_t)b * H_SZ);
    float sum = 0.f;
#pragma unroll
    for (int it = 0; it < 4; it++) {
        float4 w = wrow[lane + it * 64];
        float4 x = xrow[lane + it * 64];
        sum += w.x * x.x + w.y * x.y + w.z * x.z + w.w * x.w;
    }
#pragma unroll
    for (int off = 1; off < 64; off <<= 1) sum += __shfl_xor(sum, off, 64);
    if (lane == 0) dp[g] = sum + Wb_b[k] + Wc_b[k];
}

// ============================================================================
// 256x256-tile 8-phase GEMM (T2 swizzle + T3/T4 counted vmcnt + T5 setprio)
// C[m][n] = sum_h A[m][h] * Wc[n][h]; fused tanh/Wa epilogue into 16 slots.
//
// Geometry: BM=BN=256, BK=64, 8 waves (2Mx4N), 512 thr. LDS = 2buf x
// (A[256][64] + B[256][64]) bf16 = 128 KiB. Per-wave output 128x64 ->
// acc[8][4] f32x4. 16 MFMA per phase (2 M-frags x 4 N x 2 k-slices).
//
// LDS swizzle (T2, rule #21): logical byte L in a [.][64]bf16 row-major tile
// is stored at P = L ^ ((row&7)<<4). global_load_lds dest stays LINEAR;
// the SOURCE address is inverse-swizzled; ds_reads apply the same involution.
// Frag read addr: row*128 + ((ks*64 + quad*16) ^ ((l15&7)<<4)) -> 8 lanes per
// 4-bank group (b128 conflict-free minimum) instead of 16.
//
// Staging schedule (race-freedom from read order: B fully read in ph0;
// A rows 32p..+31 read in ph p):
//   ph0: stage A0(t+1) -> other buf (its last reads ended at tile t-1 ph3)
//   ph1: stage A1(t+1)
//   ph2: stage B0(t+2) -> SAME buf's B half0 (last read: this tile's ph0)
//   ph3: stage B1(t+2); s_waitcnt vmcnt(4) (A(t+1) landed; B(t+2) in flight)
// Each write is issued >=1 barrier after the last read of its region; the
// barrier after vmcnt makes landing visible to all waves. Never vmcnt(0) in
// the steady loop; tail tiles drain with vmcnt(0)/nothing.
// ============================================================================

__device__ __forceinline__ void stage_ht(const __hip_bfloat16* __restrict__ src,
                                         unsigned char* ldsHt, int srcRow0,
                                         int k0, int t) {
    // one half-tile = 128 rows x 64 cols bf16 = 16 KB = 2 x (512 thr x 16 B)
#pragma unroll
    for (int inst = 0; inst < 2; inst++) {
        int slot = inst * 512 + t;            // 16B slots; 8 slots per 128B row
        int row = slot >> 3;
        int colB = (slot & 7) << 4;           // linear LDS byte col
        int scol = colB ^ ((row & 7) << 4);   // inverse-swizzled source col
        const __hip_bfloat16* g = src + (size_t)(srcRow0 + row) * H_SZ + k0 + (scol >> 1);
        __builtin_amdgcn_global_load_lds(
            (const __attribute__((address_space(1))) void*)g,
            (__attribute__((address_space(3))) void*)(ldsHt + inst * 8192 + ((t >> 6) << 10)),
            16, 0, 0);
    }
}

template <int VM, bool SA, bool SB>
__device__ __forceinline__ void tile_phases(
    const __hip_bfloat16* __restrict__ Ag, const __hip_bfloat16* __restrict__ Bg,
    unsigned char* Acur, unsigned char* Bcur, unsigned char* Anxt,
    int row0, int col0, int kA, int kB, int t,
    int aRowByte, int bRowByte, int kOff0, int kOff1,
    f32x4 (&acc)[8][4])
{
    bf16x8 bfr[4][2];   // B-frags live across all 4 phases of the tile
#pragma unroll
    for (int ph = 0; ph < 4; ++ph) {
        bf16x8 afr[2][2];
        if (ph == 0) {
#pragma unroll
            for (int n = 0; n < 4; ++n) {
                bfr[n][0] = *(const bf16x8*)(Bcur + bRowByte + n * 2048 + kOff0);
                bfr[n][1] = *(const bf16x8*)(Bcur + bRowByte + n * 2048 + kOff1);
            }
        }
#pragma unroll
        for (int i = 0; i < 2; ++i) {
            afr[i][0] = *(const bf16x8*)(Acur + aRowByte + (ph * 2 + i) * 2048 + kOff0);
            afr[i][1] = *(const bf16x8*)(Acur + aRowByte + (ph * 2 + i) * 2048 + kOff1);
        }
        if (SA && ph == 0) stage_ht(Ag, Anxt,         row0,       kA, t);
        if (SA && ph == 1) stage_ht(Ag, Anxt + 16384, row0 + 128, kA, t);
        if (SB && ph == 2) stage_ht(Bg, Bcur,         col0,       kB, t);
        if (SB && ph == 3) stage_ht(Bg, Bcur + 16384, col0 + 128, kB, t);
        __builtin_amdgcn_s_barrier();
        asm volatile("s_waitcnt lgkmcnt(0)" ::: "memory");
        __builtin_amdgcn_sched_barrier(0);    // rule #18: pin MFMAs after the wait
        __builtin_amdgcn_s_setprio(1);
#pragma unroll
        for (int i = 0; i < 2; ++i)
#pragma unroll
            for (int ks = 0; ks < 2; ++ks)
#pragma unroll
                for (int n = 0; n < 4; ++n)
                    acc[ph * 2 + i][n] = __builtin_amdgcn_mfma_f32_16x16x32_bf16(
                        afr[i][ks], bfr[n][ks], acc[ph * 2 + i][n], 0, 0, 0);
        __builtin_amdgcn_s_setprio(0);
        if (ph == 3 && VM == 4) asm volatile("s_waitcnt vmcnt(4)" ::: "memory");
        if (ph == 3 && VM == 0) asm volatile("s_waitcnt vmcnt(0)" ::: "memory");
        __builtin_amdgcn_s_barrier();
    }
}

__global__ __launch_bounds__(512, 2) void gemm256_scores_k(
    const __hip_bfloat16* __restrict__ Ag, const __hip_bfloat16* __restrict__ Bg,
    const float* __restrict__ decp, const float* __restrict__ Wa,
    float* __restrict__ sp)
{
    __shared__ __align__(16) unsigned char lds[131072];
    const int t = threadIdx.x;
    const int wave = t >> 6, lane = t & 63;
    const int wr = wave >> 2, wc = wave & 3;     // 2x4 waves over 256x256
    const int quad = lane >> 4, l15 = lane & 15;

    // XCD swizzle: 1024 blocks = 256 rowBlks x 4 colBlks; a rowBlk's 4 colBlks
    // get ids == x (mod 8) at consecutive per-XCD slots -> A-panel L2 reuse.
    const int id = blockIdx.x;
    const int colBlk = (id >> 3) & 3;
    const int rowBlk = ((id >> 5) << 3) | (id & 7);
    const int row0 = rowBlk * 256, col0 = colBlk * 256;  // 256|2048: one batch

    const int swz = (l15 & 7) << 4;              // row&7 == l15&7 for all frags
    const int aRowByte = (wr * 128 + l15) * 128;
    const int bRowByte = (wc * 64 + l15) * 128;
    const int kOff0 = (quad * 16) ^ swz;
    const int kOff1 = (64 + quad * 16) ^ swz;

    f32x4 acc[8][4];
#pragma unroll
    for (int i = 0; i < 8; i++)
#pragma unroll
        for (int j = 0; j < 4; j++) acc[i][j] = f32x4{0.f, 0.f, 0.f, 0.f};

    unsigned char* A0l = lds;                    // buf0: A [0,32K) B [32K,64K)
    unsigned char* B0l = lds + 32768;
    unsigned char* A1l = lds + 65536;            // buf1: A [64K,96K) B [96K,128K)
    unsigned char* B1l = lds + 98304;

    // prologue: tile0 fully + tile1's B halves; vmcnt(4) leaves tile1's B in flight
    stage_ht(Bg, B0l,         col0,       0,  t);
    stage_ht(Bg, B0l + 16384, col0 + 128, 0,  t);
    stage_ht(Ag, A0l,         row0,       0,  t);
    stage_ht(Ag, A0l + 16384, row0 + 128, 0,  t);
    stage_ht(Bg, B1l,         col0,       64, t);
    stage_ht(Bg, B1l + 16384, col0 + 128, 64, t);
    asm volatile("s_waitcnt vmcnt(4)" ::: "memory");
    __builtin_amdgcn_s_barrier();

    // 16 K-tiles of 64: steady loop t=0..13, then drain tiles 14 and 15
#pragma unroll 2
    for (int tt = 0; tt < 14; ++tt) {
        unsigned char* Ac = (tt & 1) ? A1l : A0l;
        unsigned char* Bc = (tt & 1) ? B1l : B0l;
        unsigned char* An = (tt & 1) ? A0l : A1l;
        tile_phases<4, true, true>(Ag, Bg, Ac, Bc, An, row0, col0,
                                   (tt + 1) * 64, (tt + 2) * 64, t,
                                   aRowByte, bRowByte, kOff0, kOff1, acc);
    }
    tile_phases<0, true, false>(Ag, Bg, A0l, B0l, A1l, row0, col0,
                                15 * 64, 0, t, aRowByte, bRowByte, kOff0, kOff1, acc);
    tile_phases<-1, false, false>(Ag, Bg, A1l, B1l, A0l, row0, col0,
                                  0, 0, t, aRowByte, bRowByte, kOff0, kOff1, acc);

    // fused epilogue: partial_m = sum_n Wa[n]*tanh(C[m][n]+decp[b][n])
    const int b = row0 >> 11;
    float wa_j[4], dp_j[4];
#pragma unroll
    for (int n = 0; n < 4; ++n) {
        int c = col0 + wc * 64 + n * 16 + l15;
        wa_j[n] = Wa[c];
        dp_j[n] = decp[b * K_SZ + c];
    }
    const int slotIdx = colBlk * 4 + wc;   // 16 partial slots per row
#pragma unroll
    for (int m = 0; m < 8; ++m) {
#pragma unroll
        for (int r = 0; r < 4; ++r) {
            float tsum = 0.f;
#pragma unroll
            for (int n = 0; n < 4; ++n)
                tsum += wa_j[n] * fast_tanh(acc[m][n][r] + dp_j[n]);
            // C/D layout: row=(lane>>4)*4+reg, col=lane&15 -> reduce 16 cols
#pragma unroll
            for (int off = 1; off < 16; off <<= 1) tsum += __shfl_xor(tsum, off, 64);
            if (l15 == 0) {
                int mrow = row0 + wr * 128 + m * 16 + quad * 4 + r;
                sp[(size_t)slotIdx * M_SZ + mrow] = tsum;
            }
        }
    }
}

// ---- legacy 128x128 GEMM (kept as the fp32-A fallback when ws is small) ----

template <bool AF32>
__global__ __launch_bounds__(256) void gemm_scores_k(
    const void* __restrict__ Aptr, const __hip_bfloat16* __restrict__ Bw,
    const float* __restrict__ decp, const float* __restrict__ Wa,
    float* __restrict__ sp) {
    constexpr int ABYTES = AF32 ? 128 * 32 * 4 : 128 * 32 * 2;
    __shared__ __align__(16) unsigned char AsmRaw[ABYTES];
    __shared__ __align__(16) unsigned char BsmRaw[128 * 32 * 2];

    const int t = threadIdx.x;
    const int wave = t >> 6;
    const int lane = t & 63;
    const int wm = wave >> 1, wn = wave & 1;
    const int quad = lane >> 4;
    const int l15 = lane & 15;

    const int id = blockIdx.x;
    const int colBlk = (id >> 3) & 7;
    const int rowBlk = ((id >> 6) << 3) | (id & 7);
    const int row0 = rowBlk * 128;
    const int col0 = colBlk * 128;
    const int b = row0 >> 11;

    f32x4 acc[4][4];
#pragma unroll
    for (int i = 0; i < 4; i++)
#pragma unroll
        for (int j = 0; j < 4; j++) acc[i][j] = f32x4{0.f, 0.f, 0.f, 0.f};

    const __hip_bfloat16* Ab = (const __hip_bfloat16*)Aptr;
    const float* Af = (const float*)Aptr;

    for (int k0 = 0; k0 < H_SZ; k0 += 32) {
        if constexpr (AF32) {
#pragma unroll
            for (int inst = 0; inst < 4; inst++) {
                int slot = inst * 256 + t;
                int r = slot >> 3, c4 = slot & 7;
                const float* g = Af + (size_t)(row0 + r) * H_SZ + k0 + c4 * 4;
                __builtin_amdgcn_global_load_lds(
                    (const __attribute__((address_space(1))) void*)g,
                    (__attribute__((address_space(3))) void*)(AsmRaw + inst * 4096 + wave * 1024),
                    16, 0, 0);
            }
        } else {
#pragma unroll
            for (int inst = 0; inst < 2; inst++) {
                int slot = inst * 256 + t;
                int r = slot >> 2, c8 = slot & 3;
                const __hip_bfloat16* g = Ab + (size_t)(row0 + r) * H_SZ + k0 + c8 * 8;
                __builtin_amdgcn_global_load_lds(
                    (const __attribute__((address_space(1))) void*)g,
                    (__attribute__((address_space(3))) void*)(AsmRaw + inst * 4096 + wave * 1024),
                    16, 0, 0);
            }
        }
#pragma unroll
        for (int inst = 0; inst < 2; inst++) {
            int slot = inst * 256 + t;
            int r = slot >> 2, c8 = slot & 3;
            const __hip_bfloat16* g = Bw + (size_t)(col0 + r) * H_SZ + k0 + c8 * 8;
            __builtin_amdgcn_global_load_lds(
                (const __attribute__((address_space(1))) void*)g,
                (__attribute__((address_space(3))) void*)(BsmRaw + inst * 4096 + wave * 1024),
                16, 0, 0);
        }
        __syncthreads();

        bf16x8 afr[4], bfr[4];
#pragma unroll
        for (int i = 0; i < 4; i++) {
            int r = wm * 64 + i * 16 + l15;
            if constexpr (AF32) {
                const float* ap = (const float*)AsmRaw + r * 32 + quad * 8;
                f32x4 lo = *(const f32x4*)ap;
                f32x4 hi = *(const f32x4*)(ap + 4);
                bf16x8 v;
                v[0] = f2bf_rne(lo[0]); v[1] = f2bf_rne(lo[1]);
                v[2] = f2bf_rne(lo[2]); v[3] = f2bf_rne(lo[3]);
                v[4] = f2bf_rne(hi[0]); v[5] = f2bf_rne(hi[1]);
                v[6] = f2bf_rne(hi[2]); v[7] = f2bf_rne(hi[3]);
                afr[i] = v;
            } else {
                afr[i] = *(const bf16x8*)((const __hip_bfloat16*)AsmRaw + r * 32 + quad * 8);
            }
        }
#pragma unroll
        for (int j = 0; j < 4; j++) {
            int r = wn * 64 + j * 16 + l15;
            bfr[j] = *(const bf16x8*)((const __hip_bfloat16*)BsmRaw + r * 32 + quad * 8);
        }
#pragma unroll
        for (int i = 0; i < 4; i++)
#pragma unroll
            for (int j = 0; j < 4; j++)
                acc[i][j] = __builtin_amdgcn_mfma_f32_16x16x32_bf16(afr[i], bfr[j], acc[i][j], 0, 0, 0);
        __syncthreads();
    }

    float wa_j[4], dp_j[4];
#pragma unroll
    for (int j = 0; j < 4; j++) {
        int c = col0 + wn * 64 + j * 16 + l15;
        wa_j[j] = Wa[c];
        dp_j[j] = decp[b * K_SZ + c];
    }
    const int slotIdx = colBlk * 2 + wn;
#pragma unroll
    for (int i = 0; i < 4; i++) {
#pragma unroll
        for (int r = 0; r < 4; r++) {
            float tsum = 0.f;
#pragma unroll
            for (int j = 0; j < 4; j++)
                tsum += wa_j[j] * fast_tanh(acc[i][j][r] + dp_j[j]);
#pragma unroll
            for (int off = 1; off < 16; off <<= 1) tsum += __shfl_xor(tsum, off, 64);
            if (l15 == 0) {
                int m = row0 + wm * 64 + i * 16 + quad * 4 + r;
                sp[(size_t)slotIdx * M_SZ + m] = tsum;
            }
        }
    }
}

// ---- softmax over S per batch row (reduces the 16 partial slots) -----------

__global__ __launch_bounds__(256) void softmax_k(
    const float* __restrict__ sp, float* __restrict__ attn) {
    int b = blockIdx.x;
    int t = threadIdx.x;
    __shared__ float wred[4];
    __shared__ float wred2[4];
    float sc[8];
    float mx = -1e30f;
#pragma unroll
    for (int u = 0; u < 8; u++) {
        int m = b * S_SZ + t + u * 256;
        float v = 0.f;
#pragma unroll
        for (int c = 0; c < 16; c++) v += sp[(size_t)c * M_SZ + m];
        sc[u] = v;
        mx = fmaxf(mx, v);
    }
#pragma unroll
    for (int off = 1; off < 64; off <<= 1) mx = fmaxf(mx, __shfl_xor(mx, off, 64));
    if ((t & 63) == 0) wred[t >> 6] = mx;
    __syncthreads();
    mx = fmaxf(fmaxf(wred[0], wred[1]), fmaxf(wred[2], wred[3]));
    float lsum = 0.f;
#pragma unroll
    for (int u = 0; u < 8; u++) { sc[u] = expf(sc[u] - mx); lsum += sc[u]; }
#pragma unroll
    for (int off = 1; off < 64; off <<= 1) lsum += __shfl_xor(lsum, off, 64);
    if ((t & 63) == 0) wred2[t >> 6] = lsum;
    __syncthreads();
    float inv = 1.f / (wred2[0] + wred2[1] + wred2[2] + wred2[3]);
#pragma unroll
    for (int u = 0; u < 8; u++) attn[b * S_SZ + t + u * 256] = sc[u] * inv;
}

// ---- context partials: cp[c][b][h] = sum_{s in chunk c} attn[b,s]*enc[b,s,h]

template <bool BF16E>
__global__ __launch_bounds__(256) void ctx_part_k(
    const float* __restrict__ attn, const void* __restrict__ encp,
    float* __restrict__ cp) {
    int b = blockIdx.x >> 5;
    int c = blockIdx.x & 31;
    int t = threadIdx.x;
    __shared__ float wloc[64];
    if (t < 64) wloc[t] = attn[b * S_SZ + c * 64 + t];
    __syncthreads();
    float4 acc = {0.f, 0.f, 0.f, 0.f};
    if constexpr (BF16E) {
        const ushort4* ep = (const ushort4*)((const __hip_bfloat16*)encp +
                              ((size_t)b * S_SZ + (size_t)c * 64) * H_SZ);
#pragma unroll 8
        for (int s = 0; s < 64; s++) {
            float w = wloc[s];
            ushort4 v = ep[s * 256 + t];
            acc.x += w * bf2f(v.x); acc.y += w * bf2f(v.y);
            acc.z += w * bf2f(v.z); acc.w += w * bf2f(v.w);
        }
    } else {
        const float4* ep = (const float4*)((const float*)encp +
                              ((size_t)b * S_SZ + (size_t)c * 64) * H_SZ);
#pragma unroll 8
        for (int s = 0; s < 64; s++) {
            float w = wloc[s];
            float4 v = ep[s * 256 + t];
            acc.x += w * v.x; acc.y += w * v.y;
            acc.z += w * v.z; acc.w += w * v.w;
        }
    }
    ((float4*)(cp + ((size_t)c * B_SZ + b) * H_SZ))[t] = acc;
}

__global__ void ctx_red_k(const float* __restrict__ cp, float* __restrict__ out) {
    int i = blockIdx.x * blockDim.x + threadIdx.x;   // 0..32767
    float s = 0.f;
#pragma unroll
    for (int c = 0; c < 32; c++) s += cp[(size_t)c * (B_SZ * H_SZ) + i];
    out[i] = s;
}

// ---- launch -----------------------------------------------------------------

extern "C" void kernel_launch(void* const* d_in, const int* in_sizes, int n_in,
                              void* d_out, int out_size, void* d_ws, size_t ws_size,
                              hipStream_t stream) {
    const float* dec  = (const float*)d_in[0];
    const float* enc  = (const float*)d_in[1];
    const float* Wa_w = (const float*)d_in[2];
    // d_in[3] = Wa_b: softmax is shift-invariant, scalar bias cancels exactly.
    const float* Wb_w = (const float*)d_in[4];
    const float* Wb_b = (const float*)d_in[5];
    const float* Wc_w = (const float*)d_in[6];
    const float* Wc_b = (const float*)d_in[7];
    float* out = (float*)d_out;

    char* ws = (char*)d_ws;
    size_t off = 0;
    auto alloc = [&](size_t bytes) -> void* {
        void* p = ws + off;
        off += (bytes + 255) & ~(size_t)255;
        return p;
    };
    __hip_bfloat16* wc_bf = (__hip_bfloat16*)alloc((size_t)K_SZ * H_SZ * 2);
    float* dp     = (float*)alloc((size_t)B_SZ * K_SZ * 4);
    float* spart  = (float*)alloc((size_t)16 * M_SZ * 4);
    float* attn   = (float*)alloc((size_t)B_SZ * S_SZ * 4);
    float* cpart  = (float*)alloc((size_t)32 * B_SZ * H_SZ * 4);
    __hip_bfloat16* enc_bf = (__hip_bfloat16*)alloc((size_t)M_SZ * H_SZ * 2);
    const bool useBf16A = (off <= ws_size);   // ws_size-dependent only: same every call

    cvt_bf16_k<<<512, 256, 0, stream>>>(Wc_w, wc_bf, K_SZ * H_SZ / 8);
    if (useBf16A)
        cvt_bf16_k<<<8192, 256, 0, stream>>>(enc, enc_bf, M_SZ * H_SZ / 8);
    decproj_k<<<8192, 256, 0, stream>>>(dec, Wb_w, Wb_b, Wc_b, dp);
    if (useBf16A)
        gemm256_scores_k<<<(M_SZ / 256) * (K_SZ / 256), 512, 0, stream>>>(enc_bf, wc_bf, dp, Wa_w, spart);
    else
        gemm_scores_k<true><<<(M_SZ / 128) * 8, 256, 0, stream>>>(enc, wc_bf, dp, Wa_w, spart);
    softmax_k<<<B_SZ, 256, 0, stream>>>(spart, attn);
    if (useBf16A)
        ctx_part_k<true><<<B_SZ * 32, 256, 0, stream>>>(attn, enc_bf, cpart);
    else
        ctx_part_k<false><<<B_SZ * 32, 256, 0, stream>>>(attn, enc, cpart);
    ctx_red_k<<<128, 256, 0, stream>>>(cpart, out);
}